// Round 1
// baseline (1138.618 us; speedup 1.0000x reference)
//
#include <hip/hip_runtime.h>

#define NB 16    // N*G
#define CD 64    // C == Cv
#define HD 2048  // H
#define TS 64    // tile size
#define PD 68    // padded stride for transposed LDS tiles

typedef union { float4 v; float f[4]; } F4;

__device__ __forceinline__ float4 ld4(const float* p){ return *reinterpret_cast<const float4*>(p); }
__device__ __forceinline__ void st4(float* p, float4 v){ *reinterpret_cast<float4*>(p) = v; }

// bias[bg][j] = 0.5*beta*sum_c mu[bg][c][j]^2   (mu never changes -> computed once)
__global__ void k_bias(const float* __restrict__ mu, const float* __restrict__ beta,
                       float* __restrict__ bias)
{
    int bg = blockIdx.y;
    int j  = blockIdx.x*256 + threadIdx.x;
    const float* m = mu + (size_t)bg*CD*HD + j;
    float s = 0.f;
    #pragma unroll
    for (int c=0;c<CD;c++){ float v = m[(size_t)c*HD]; s = fmaf(v, v, s); }
    bias[(size_t)bg*HD + j] = 0.5f * beta[0] * s;
}

// r[bg][i] = sum_j exp(a * (q_i . z_j) + bias_j)   (no max subtraction needed; see bounds)
__global__ __launch_bounds__(256,2) void k_rowsum(
    const float* __restrict__ q, const float* __restrict__ z,
    const float* __restrict__ bias, const float* __restrict__ alpha,
    float* __restrict__ r)
{
    const int bg = blockIdx.y;
    const int i0 = blockIdx.x*TS;
    const int tid = threadIdx.x;
    const int tx = tid & 15, ty = tid >> 4;
    const float a = alpha[0];
    __shared__ __align__(16) float q1[CD*TS];  // [c][i]
    __shared__ __align__(16) float z1[CD*TS];  // [c][j]
    const float* qb = q + (size_t)bg*CD*HD;
    const float* zb = z + (size_t)bg*CD*HD;
    const float* bb = bias + (size_t)bg*HD;

    #pragma unroll
    for (int k=0;k<4;k++){
        int f = tid + 256*k, c = f>>4, p = (f&15)*4;
        st4(&q1[c*TS+p], ld4(qb + (size_t)c*HD + i0 + p));
    }
    float racc[4] = {0.f,0.f,0.f,0.f};
    for (int j0=0;j0<HD;j0+=TS){
        __syncthreads();
        #pragma unroll
        for (int k=0;k<4;k++){
            int f = tid + 256*k, c = f>>4, p = (f&15)*4;
            st4(&z1[c*TS+p], ld4(zb + (size_t)c*HD + j0 + p));
        }
        __syncthreads();
        float s[4][4] = {{0.f}};
        #pragma unroll 8
        for (int c=0;c<CD;c++){
            F4 qa, zc;
            qa.v = ld4(&q1[c*TS + ty*4]);
            zc.v = ld4(&z1[c*TS + tx*4]);
            #pragma unroll
            for (int ii=0;ii<4;ii++)
                #pragma unroll
                for (int jj=0;jj<4;jj++)
                    s[ii][jj] = fmaf(qa.f[ii], zc.f[jj], s[ii][jj]);
        }
        F4 bj; bj.v = ld4(bb + j0 + tx*4);
        #pragma unroll
        for (int ii=0;ii<4;ii++)
            #pragma unroll
            for (int jj=0;jj<4;jj++)
                racc[ii] += __expf(fmaf(a, s[ii][jj], bj.f[jj]));
    }
    #pragma unroll
    for (int ii=0;ii<4;ii++){
        float v = racc[ii];
        v += __shfl_xor(v, 1);
        v += __shfl_xor(v, 2);
        v += __shfl_xor(v, 4);
        v += __shfl_xor(v, 8);
        if (tx == 0) r[(size_t)bg*HD + i0 + ty*4 + ii] = v;
    }
}

// zeta update: block owns (bg, j-tile); recompute S over all i, w = e/r_i,
// zout[c][j] = (sum_i w_ij q_ci) / (sum_i w_ij).  In-place safe (own columns only).
__global__ __launch_bounds__(256,2) void k_update(
    const float* __restrict__ q, const float* __restrict__ zin, float* __restrict__ zout,
    const float* __restrict__ bias, const float* __restrict__ alpha,
    const float* __restrict__ r)
{
    const int bg = blockIdx.y;
    const int j0 = blockIdx.x*TS;
    const int tid = threadIdx.x;
    const int tx = tid & 15, ty = tid >> 4;
    const float a = alpha[0];
    __shared__ __align__(16) float z1[CD*TS];  // [c][j], resident whole block
    __shared__ __align__(16) float q2[TS*PD];  // [i][c] transposed, padded
    __shared__ __align__(16) float wl[TS*TS];  // [i][j]; tail rows reused for den reduce
    const float* qb = q + (size_t)bg*CD*HD;
    const float* zb = zin + (size_t)bg*CD*HD;

    #pragma unroll
    for (int k=0;k<4;k++){
        int f = tid + 256*k, c = f>>4, p = (f&15)*4;
        st4(&z1[c*TS+p], ld4(zb + (size_t)c*HD + j0 + p));
    }
    F4 bj; bj.v = ld4(bias + (size_t)bg*HD + j0 + tx*4);
    float acc[4][4] = {{0.f}};        // (cc, jj)
    float den[4] = {0.f,0.f,0.f,0.f};

    for (int i0=0;i0<HD;i0+=TS){
        __syncthreads();              // prev iter's q2/wl consumers done
        #pragma unroll
        for (int k=0;k<4;k++){
            int f = tid + 256*k, c = f>>4, p = (f&15)*4;
            F4 v; v.v = ld4(qb + (size_t)c*HD + i0 + p);
            #pragma unroll
            for (int m=0;m<4;m++) q2[(p+m)*PD + c] = v.f[m];
        }
        __syncthreads();
        float s[4][4] = {{0.f}};      // i = ty*4+ii (local), j = tx*4+jj
        #pragma unroll 4
        for (int c=0;c<CD;c++){
            F4 zc; zc.v = ld4(&z1[c*TS + tx*4]);
            float qv[4];
            #pragma unroll
            for (int ii=0;ii<4;ii++) qv[ii] = q2[(ty*4+ii)*PD + c];
            #pragma unroll
            for (int ii=0;ii<4;ii++)
                #pragma unroll
                for (int jj=0;jj<4;jj++)
                    s[ii][jj] = fmaf(qv[ii], zc.f[jj], s[ii][jj]);
        }
        F4 rv; rv.v = ld4(r + (size_t)bg*HD + i0 + ty*4);
        float rinv[4];
        #pragma unroll
        for (int ii=0;ii<4;ii++) rinv[ii] = 1.0f / rv.f[ii];
        float w[4][4];
        #pragma unroll
        for (int ii=0;ii<4;ii++)
            #pragma unroll
            for (int jj=0;jj<4;jj++)
                w[ii][jj] = __expf(fmaf(a, s[ii][jj], bj.f[jj])) * rinv[ii];
        #pragma unroll
        for (int jj=0;jj<4;jj++)
            den[jj] += (w[0][jj]+w[1][jj]) + (w[2][jj]+w[3][jj]);
        #pragma unroll
        for (int ii=0;ii<4;ii++){
            F4 t;
            #pragma unroll
            for (int jj=0;jj<4;jj++) t.f[jj] = w[ii][jj];
            st4(&wl[(ty*4+ii)*TS + tx*4], t.v);
        }
        __syncthreads();
        #pragma unroll 8
        for (int i=0;i<TS;i++){       // second matmul: acc[c][j] += q[c,i]*w[i,j]
            F4 qv4, wv;
            qv4.v = ld4(&q2[i*PD + ty*4]);
            wv.v  = ld4(&wl[i*TS + tx*4]);
            #pragma unroll
            for (int cc=0;cc<4;cc++)
                #pragma unroll
                for (int jj=0;jj<4;jj++)
                    acc[cc][jj] = fmaf(qv4.f[cc], wv.f[jj], acc[cc][jj]);
        }
    }
    // den reduction across ty (cross-wave -> LDS; reuse wl)
    __syncthreads();
    {
        F4 d;
        #pragma unroll
        for (int jj=0;jj<4;jj++) d.f[jj] = den[jj];
        st4(&wl[ty*TS + tx*4], d.v);
    }
    __syncthreads();
    if (tid < TS){
        float t = 0.f;
        #pragma unroll
        for (int y=0;y<16;y++) t += wl[y*TS + tid];
        wl[1024 + tid] = t;
    }
    __syncthreads();
    float dinv[4];
    #pragma unroll
    for (int jj=0;jj<4;jj++) dinv[jj] = 1.0f / wl[1024 + tx*4 + jj];
    float* zo = zout + (size_t)bg*CD*HD;
    #pragma unroll
    for (int cc=0;cc<4;cc++){
        F4 o;
        #pragma unroll
        for (int jj=0;jj<4;jj++) o.f[jj] = acc[cc][jj] * dinv[jj];
        st4(zo + (size_t)(ty*4+cc)*HD + j0 + tx*4, o.v);
    }
}

// final: v[c][i] = (sum_j e_ij mu_cj) / (sum_j e_ij) — fused single pass (flash-style,
// no max needed).  Block owns (bg, i-tile); zel doubles as z-tile then e-tile.
__global__ __launch_bounds__(256,2) void k_final(
    const float* __restrict__ q, const float* __restrict__ z, const float* __restrict__ mu,
    const float* __restrict__ bias, const float* __restrict__ alpha,
    float* __restrict__ out)
{
    const int bg = blockIdx.y;
    const int i0 = blockIdx.x*TS;
    const int tid = threadIdx.x;
    const int tx = tid & 15, ty = tid >> 4;
    const float a = alpha[0];
    __shared__ __align__(16) float q1[CD*TS];   // [c][i], resident
    __shared__ __align__(16) float zel[TS*PD];  // z tile [c][j] -> e tile [j][i]
    __shared__ __align__(16) float mt[TS*PD];   // mu^T [j][c]
    __shared__ float rl[TS];
    const float* qb = q + (size_t)bg*CD*HD;
    const float* zb = z + (size_t)bg*CD*HD;
    const float* mb = mu + (size_t)bg*CD*HD;
    const float* bb = bias + (size_t)bg*HD;

    #pragma unroll
    for (int k=0;k<4;k++){
        int f = tid + 256*k, c = f>>4, p = (f&15)*4;
        st4(&q1[c*TS+p], ld4(qb + (size_t)c*HD + i0 + p));
    }
    float acc[4][4] = {{0.f}};        // (cc, ii2) over (c, i)
    float racc[4] = {0.f,0.f,0.f,0.f};
    for (int j0=0;j0<HD;j0+=TS){
        __syncthreads();              // prev matmul2 done with zel/mt
        #pragma unroll
        for (int k=0;k<4;k++){
            int f = tid + 256*k, c = f>>4, p = (f&15)*4;
            st4(&zel[c*PD+p], ld4(zb + (size_t)c*HD + j0 + p));
            F4 v; v.v = ld4(mb + (size_t)c*HD + j0 + p);
            #pragma unroll
            for (int m=0;m<4;m++) mt[(p+m)*PD + c] = v.f[m];
        }
        __syncthreads();
        float s[4][4] = {{0.f}};      // i = ty*4+ii, j = tx*4+jj
        #pragma unroll 8
        for (int c=0;c<CD;c++){
            F4 qa, zc;
            qa.v = ld4(&q1[c*TS + ty*4]);
            zc.v = ld4(&zel[c*PD + tx*4]);
            #pragma unroll
            for (int ii=0;ii<4;ii++)
                #pragma unroll
                for (int jj=0;jj<4;jj++)
                    s[ii][jj] = fmaf(qa.f[ii], zc.f[jj], s[ii][jj]);
        }
        F4 bj; bj.v = ld4(bb + j0 + tx*4);
        float e[4][4];
        #pragma unroll
        for (int ii=0;ii<4;ii++)
            #pragma unroll
            for (int jj=0;jj<4;jj++)
                e[ii][jj] = __expf(fmaf(a, s[ii][jj], bj.f[jj]));
        #pragma unroll
        for (int ii=0;ii<4;ii++)
            racc[ii] += (e[ii][0]+e[ii][1]) + (e[ii][2]+e[ii][3]);
        __syncthreads();              // all reads of zel (z tile) done
        #pragma unroll
        for (int jj=0;jj<4;jj++){
            F4 t;
            #pragma unroll
            for (int ii=0;ii<4;ii++) t.f[ii] = e[ii][jj];
            st4(&zel[(tx*4+jj)*PD + ty*4], t.v);   // e^T: [j][i]
        }
        __syncthreads();
        #pragma unroll 8
        for (int j=0;j<TS;j++){       // acc[c][i] += mu[c][j] * e[i][j]
            F4 mv, ev;
            mv.v = ld4(&mt[j*PD + ty*4]);
            ev.v = ld4(&zel[j*PD + tx*4]);
            #pragma unroll
            for (int cc=0;cc<4;cc++)
                #pragma unroll
                for (int ii=0;ii<4;ii++)
                    acc[cc][ii] = fmaf(mv.f[cc], ev.f[ii], acc[cc][ii]);
        }
    }
    #pragma unroll
    for (int ii=0;ii<4;ii++){
        float v = racc[ii];
        v += __shfl_xor(v, 1);
        v += __shfl_xor(v, 2);
        v += __shfl_xor(v, 4);
        v += __shfl_xor(v, 8);
        if (tx == 0) rl[ty*4 + ii] = v;
    }
    __syncthreads();
    float rinv[4];
    #pragma unroll
    for (int ii=0;ii<4;ii++) rinv[ii] = 1.0f / rl[tx*4 + ii];
    float* ob = out + (size_t)bg*CD*HD;
    #pragma unroll
    for (int cc=0;cc<4;cc++){
        F4 o;
        #pragma unroll
        for (int ii=0;ii<4;ii++) o.f[ii] = acc[cc][ii] * rinv[ii];
        st4(ob + (size_t)(ty*4+cc)*HD + i0 + tx*4, o.v);
    }
}

extern "C" void kernel_launch(void* const* d_in, const int* in_sizes, int n_in,
                              void* d_out, int out_size, void* d_ws, size_t ws_size,
                              hipStream_t stream)
{
    (void)in_sizes; (void)n_in; (void)out_size; (void)ws_size;
    const float* q     = (const float*)d_in[0];
    const float* zeta  = (const float*)d_in[1];
    const float* alpha = (const float*)d_in[2];
    const float* mu    = (const float*)d_in[3];
    const float* beta  = (const float*)d_in[4];
    float* out = (float*)d_out;
    float* ws  = (float*)d_ws;

    float* bias = ws;                          // NB*HD floats
    float* r    = ws + (size_t)NB*HD;          // NB*HD floats
    float* z    = ws + (size_t)2*NB*HD;        // NB*CD*HD floats (~8 MB)

    dim3 blk(256,1,1);
    k_bias  <<<dim3(HD/256, NB), blk, 0, stream>>>(mu, beta, bias);
    // t=0: weights from input zeta -> new zeta into ws
    k_rowsum<<<dim3(HD/TS, NB), blk, 0, stream>>>(q, zeta, bias, alpha, r);
    k_update<<<dim3(HD/TS, NB), blk, 0, stream>>>(q, zeta, z, bias, alpha, r);
    // t=1: in-place zeta update
    k_rowsum<<<dim3(HD/TS, NB), blk, 0, stream>>>(q, z, bias, alpha, r);
    k_update<<<dim3(HD/TS, NB), blk, 0, stream>>>(q, z, z, bias, alpha, r);
    // t=2: fused weights + value mixdown
    k_final <<<dim3(HD/TS, NB), blk, 0, stream>>>(q, z, mu, bias, alpha, out);
}

// Round 2
// 518.328 us; speedup vs baseline: 2.1967x; 2.1967x over previous
//
#include <hip/hip_runtime.h>

#define NB 16    // N*G
#define CD 64    // C == Cv
#define HD 2048  // H

typedef unsigned short u16;
typedef __attribute__((ext_vector_type(8))) short s16x8;  // 8 bf16 (4 VGPRs)
typedef __attribute__((ext_vector_type(4))) float f32x4;  // MFMA C/D

__device__ __forceinline__ u16 f2bf(float x){
    unsigned u = __float_as_uint(x);
    u += 0x7FFFu + ((u >> 16) & 1u);   // RNE
    return (u16)(u >> 16);
}
__device__ __forceinline__ float bf2f(u16 h){ return __uint_as_float(((unsigned)h) << 16); }
__device__ __forceinline__ void split2(float x, u16& h, u16& l){
    h = f2bf(x); l = f2bf(x - bf2f(h));   // x - hi is exact in fp32
}
union Frag { uint4 q; s16x8 s; };
__device__ __forceinline__ s16x8 ld8(const u16* p){ Frag f; f.q = *(const uint4*)p; return f.s; }
__device__ __forceinline__ f32x4 mfma16(s16x8 a, s16x8 b, f32x4 c){
    return __builtin_amdgcn_mfma_f32_16x16x32_bf16(a, b, c, 0, 0, 0);
}
// fp32-emulating triple MFMA: hi*hi + hi*lo + lo*hi
__device__ __forceinline__ f32x4 mm3(s16x8 ah, s16x8 al, s16x8 bh, s16x8 bl, f32x4 c){
    c = mfma16(ah, bh, c);
    c = mfma16(ah, bl, c);
    c = mfma16(al, bh, c);
    return c;
}
__device__ __forceinline__ f32x4 z4(){ f32x4 v = {0.f,0.f,0.f,0.f}; return v; }

// ---------------- prep kernels ----------------

// elementwise fp32 -> bf16 hi/lo, layout preserved
__global__ void k_convert(const float* __restrict__ src, u16* __restrict__ dh,
                          u16* __restrict__ dl, int n4)
{
    int idx = blockIdx.x*256 + threadIdx.x;
    if (idx >= n4) return;
    float4 v = ((const float4*)src)[idx];
    ushort4 h, l;
    split2(v.x, h.x, l.x); split2(v.y, h.y, l.y);
    split2(v.z, h.z, l.z); split2(v.w, h.w, l.w);
    ((ushort4*)dh)[idx] = h;
    ((ushort4*)dl)[idx] = l;
}

// fp32 [bg][c=64][h=2048] -> bf16 hi/lo [bg][h][c=64]
__global__ void k_transpose(const float* __restrict__ src, u16* __restrict__ dh,
                            u16* __restrict__ dl)
{
    int bg = blockIdx.y, h0 = blockIdx.x*128, tid = threadIdx.x;
    __shared__ float ft[CD][132];
    #pragma unroll
    for (int k=0;k<8;k++){
        int flat = tid + 256*k;
        int c = flat >> 5, p = (flat & 31)*4;
        *(float4*)&ft[c][p] = *(const float4*)(src + ((size_t)bg*CD + c)*HD + h0 + p);
    }
    __syncthreads();
    int hl = tid >> 1, c0 = (tid & 1)*32;
    union { u16 u[32]; uint4 q[4]; } oh, ol;
    #pragma unroll
    for (int m=0;m<32;m++){
        float x = ft[c0+m][hl];
        u16 hh; split2(x, hh, ol.u[m]); oh.u[m] = hh;
    }
    size_t base = ((size_t)bg*HD + h0 + hl)*CD + c0;
    #pragma unroll
    for (int t=0;t<4;t++){
        *((uint4*)(dh + base) + t) = oh.q[t];
        *((uint4*)(dl + base) + t) = ol.q[t];
    }
}

// bias[bg][j] = 0.5*beta*sum_c mu^2
__global__ void k_bias(const float* __restrict__ mu, const float* __restrict__ beta,
                       float* __restrict__ bias)
{
    int bg = blockIdx.y;
    int j  = blockIdx.x*256 + threadIdx.x;
    const float* m = mu + (size_t)bg*CD*HD + j;
    float s = 0.f;
    #pragma unroll
    for (int c=0;c<CD;c++){ float v = m[(size_t)c*HD]; s = fmaf(v, v, s); }
    bias[(size_t)bg*HD + j] = 0.5f * beta[0] * s;
}

// ---------------- main MFMA kernels ----------------
// S[i][j] = sum_c q[c][i] z[c][j]; logits = a*S + bias_j (z2 terms cancel, row const drops)

// r[i] = sum_j exp(a*S+bias_j). Block: 64 i-rows (m), sweeps j; waves split n.
__global__ __launch_bounds__(256,2) void k_rowsum(
    const u16* __restrict__ qTh, const u16* __restrict__ qTl,
    const u16* __restrict__ zTh, const u16* __restrict__ zTl,
    const float* __restrict__ bias, const float* __restrict__ alpha,
    float* __restrict__ r)
{
    const int bg = blockIdx.y, i0 = blockIdx.x*64;
    const int tid = threadIdx.x, wave = tid>>6, lane = tid&63, ln = lane&15, quad = lane>>4;
    const float a = alpha[0];
    __shared__ float rpart[4][64];

    s16x8 Ah[4][2], Al[4][2];     // resident q^T frags: rows i0..i0+63
    #pragma unroll
    for (int mt=0;mt<4;mt++)
        #pragma unroll
        for (int ks=0;ks<2;ks++){
            size_t off = ((size_t)bg*HD + i0 + mt*16 + ln)*CD + ks*32 + quad*8;
            Ah[mt][ks] = ld8(qTh + off);
            Al[mt][ks] = ld8(qTl + off);
        }
    float racc[16];
    #pragma unroll
    for (int k=0;k<16;k++) racc[k] = 0.f;
    const float* bb = bias + (size_t)bg*HD;

    for (int j0=0;j0<HD;j0+=128){
        f32x4 acc[4][2];
        #pragma unroll
        for (int mt=0;mt<4;mt++){ acc[mt][0]=z4(); acc[mt][1]=z4(); }
        #pragma unroll
        for (int ks=0;ks<2;ks++){
            s16x8 Bh[2], Bl[2];
            #pragma unroll
            for (int nt=0;nt<2;nt++){
                size_t off = ((size_t)bg*HD + j0 + wave*32 + nt*16 + ln)*CD + ks*32 + quad*8;
                Bh[nt] = ld8(zTh + off);
                Bl[nt] = ld8(zTl + off);
            }
            #pragma unroll
            for (int mt=0;mt<4;mt++)
                #pragma unroll
                for (int nt=0;nt<2;nt++)
                    acc[mt][nt] = mm3(Ah[mt][ks], Al[mt][ks], Bh[nt], Bl[nt], acc[mt][nt]);
        }
        float bj[2];
        #pragma unroll
        for (int nt=0;nt<2;nt++) bj[nt] = bb[j0 + wave*32 + nt*16 + ln];
        #pragma unroll
        for (int mt=0;mt<4;mt++)
            #pragma unroll
            for (int nt=0;nt<2;nt++)
                #pragma unroll
                for (int rx=0;rx<4;rx++)
                    racc[mt*4+rx] += __expf(fmaf(a, acc[mt][nt][rx], bj[nt]));
    }
    #pragma unroll
    for (int k=0;k<16;k++){
        float v = racc[k];
        v += __shfl_xor(v,1); v += __shfl_xor(v,2);
        v += __shfl_xor(v,4); v += __shfl_xor(v,8);
        racc[k] = v;
    }
    if (ln == 0){
        #pragma unroll
        for (int mt=0;mt<4;mt++)
            #pragma unroll
            for (int rx=0;rx<4;rx++)
                rpart[wave][mt*16 + quad*4 + rx] = racc[mt*4+rx];
    }
    __syncthreads();
    if (tid < 64)
        r[(size_t)bg*HD + i0 + tid] = rpart[0][tid]+rpart[1][tid]+rpart[2][tid]+rpart[3][tid];
}

// zeta update. Block: 64 j-cols (n), sweeps i (m, 128/step); waves split m in phase A.
// Phase B: zeta_num[c][j] = sum_i q[c][i] w[i][j]; in-place write of z^T at end.
__global__ __launch_bounds__(256,2) void k_update(
    const u16* __restrict__ qTh, const u16* __restrict__ qTl,
    u16* zTh, u16* zTl,                               // read then overwritten (own rows only)
    const u16* __restrict__ qNh, const u16* __restrict__ qNl,
    const float* __restrict__ bias, const float* __restrict__ alpha,
    const float* __restrict__ r)
{
    const int bg = blockIdx.y, j0 = blockIdx.x*64;
    const int tid = threadIdx.x, wave = tid>>6, lane = tid&63, ln = lane&15, quad = lane>>4;
    const int cm = (wave&1)*32, jn = (wave>>1)*32;
    const float a = alpha[0];
    __shared__ u16 wlh[64*128], wll[64*128];          // w^T tile [j][i], XOR-swizzled 16B blocks
    __shared__ float denl[4][64];

    s16x8 Bh[4][2], Bl[4][2];     // resident z^T frags: rows j0..j0+63 (read before any write)
    #pragma unroll
    for (int nt=0;nt<4;nt++)
        #pragma unroll
        for (int ks=0;ks<2;ks++){
            size_t off = ((size_t)bg*HD + j0 + nt*16 + ln)*CD + ks*32 + quad*8;
            Bh[nt][ks] = ld8(zTh + off);
            Bl[nt][ks] = ld8(zTl + off);
        }
    float bj[4];
    #pragma unroll
    for (int nt=0;nt<4;nt++) bj[nt] = bias[(size_t)bg*HD + j0 + nt*16 + ln];

    f32x4 acc2[2][2] = {{z4(),z4()},{z4(),z4()}};
    float den[4] = {0.f,0.f,0.f,0.f};

    for (int is=0;is<HD;is+=128){
        // phase A: S tile (m = i: wave*32 + 2 mtiles; n = j: 4 ntiles)
        f32x4 acc1[2][4];
        #pragma unroll
        for (int mt=0;mt<2;mt++)
            #pragma unroll
            for (int nt=0;nt<4;nt++) acc1[mt][nt] = z4();
        #pragma unroll
        for (int ks=0;ks<2;ks++){
            s16x8 Ah[2], Al[2];
            #pragma unroll
            for (int mt=0;mt<2;mt++){
                size_t off = ((size_t)bg*HD + is + wave*32 + mt*16 + ln)*CD + ks*32 + quad*8;
                Ah[mt] = ld8(qTh + off);
                Al[mt] = ld8(qTl + off);
            }
            #pragma unroll
            for (int mt=0;mt<2;mt++)
                #pragma unroll
                for (int nt=0;nt<4;nt++)
                    acc1[mt][nt] = mm3(Ah[mt], Al[mt], Bh[nt][ks], Bl[nt][ks], acc1[mt][nt]);
        }
        float ri[8];
        #pragma unroll
        for (int mt=0;mt<2;mt++)
            #pragma unroll
            for (int rx=0;rx<4;rx++)
                ri[mt*4+rx] = __builtin_amdgcn_rcpf(r[(size_t)bg*HD + is + wave*32 + mt*16 + quad*4 + rx]);
        __syncthreads();   // prev step's phase-B reads of wl done
        #pragma unroll
        for (int mt=0;mt<2;mt++)
            #pragma unroll
            for (int nt=0;nt<4;nt++){
                u16 hh[4], ll[4];
                #pragma unroll
                for (int rx=0;rx<4;rx++){
                    float w = __expf(fmaf(a, acc1[mt][nt][rx], bj[nt])) * ri[mt*4+rx];
                    den[nt] += w;
                    split2(w, hh[rx], ll[rx]);
                }
                int row = nt*16 + ln;                        // j-local
                int c4  = wave*32 + mt*16 + quad*4;          // i-local
                int off = (row<<7) + ((((c4>>3) ^ (row&15))<<3) | (c4&7));
                *(ushort4*)&wlh[off] = make_ushort4(hh[0],hh[1],hh[2],hh[3]);
                *(ushort4*)&wll[off] = make_ushort4(ll[0],ll[1],ll[2],ll[3]);
            }
        __syncthreads();
        // phase B: acc2[c][j] += qN * w   (m = c, n = j, k = i)
        #pragma unroll
        for (int ks2=0;ks2<4;ks2++){
            s16x8 A2h[2], A2l[2], B2h[2], B2l[2];
            #pragma unroll
            for (int mtN=0;mtN<2;mtN++){
                size_t off = ((size_t)bg*CD + cm + mtN*16 + ln)*HD + is + ks2*32 + quad*8;
                A2h[mtN] = ld8(qNh + off);
                A2l[mtN] = ld8(qNl + off);
            }
            #pragma unroll
            for (int nt2=0;nt2<2;nt2++){
                int jl = jn + nt2*16 + ln;
                int ob = (jl<<7) + (((ks2*4+quad) ^ (jl&15))<<3);
                B2h[nt2] = ld8(&wlh[ob]);
                B2l[nt2] = ld8(&wll[ob]);
            }
            #pragma unroll
            for (int mtN=0;mtN<2;mtN++)
                #pragma unroll
                for (int nt2=0;nt2<2;nt2++)
                    acc2[mtN][nt2] = mm3(A2h[mtN], A2l[mtN], B2h[nt2], B2l[nt2], acc2[mtN][nt2]);
        }
    }
    // denominator reduce: quads via shfl, waves via LDS
    #pragma unroll
    for (int nt=0;nt<4;nt++){
        float v = den[nt];
        v += __shfl_xor(v,16); v += __shfl_xor(v,32);
        if (quad == 0) denl[wave][nt*16 + ln] = v;
    }
    __syncthreads();
    #pragma unroll
    for (int nt2=0;nt2<2;nt2++){
        int jl = jn + nt2*16 + ln;
        float dinv = __builtin_amdgcn_rcpf(denl[0][jl]+denl[1][jl]+denl[2][jl]+denl[3][jl]);
        #pragma unroll
        for (int mtN=0;mtN<2;mtN++){
            u16 hh[4], ll[4];
            #pragma unroll
            for (int rx=0;rx<4;rx++){
                float v = acc2[mtN][nt2][rx] * dinv;
                split2(v, hh[rx], ll[rx]);
            }
            size_t off = ((size_t)bg*HD + j0 + jl)*CD + cm + mtN*16 + quad*4;
            *(ushort4*)(zTh + off) = make_ushort4(hh[0],hh[1],hh[2],hh[3]);
            *(ushort4*)(zTl + off) = make_ushort4(ll[0],ll[1],ll[2],ll[3]);
        }
    }
}

// final: out[c][i] = (sum_j e_ij mu_cj) / (sum_j e_ij). Block: 64 i (n), sweeps j (m).
__global__ __launch_bounds__(256,2) void k_final(
    const u16* __restrict__ qTh, const u16* __restrict__ qTl,
    const u16* __restrict__ zTh, const u16* __restrict__ zTl,
    const u16* __restrict__ muh, const u16* __restrict__ mul_,
    const float* __restrict__ bias, const float* __restrict__ alpha,
    float* __restrict__ out)
{
    const int bg = blockIdx.y, i0 = blockIdx.x*64;
    const int tid = threadIdx.x, wave = tid>>6, lane = tid&63, ln = lane&15, quad = lane>>4;
    const int cm = (wave&1)*32, in_ = (wave>>1)*32;
    const float a = alpha[0];
    __shared__ u16 elh[64*128], ell[64*128];          // e^T tile [i][j], swizzled
    __shared__ float rl2[4][64];

    s16x8 Bh[4][2], Bl[4][2];     // resident q^T frags: rows i0..i0+63 (n operand)
    #pragma unroll
    for (int nt=0;nt<4;nt++)
        #pragma unroll
        for (int ks=0;ks<2;ks++){
            size_t off = ((size_t)bg*HD + i0 + nt*16 + ln)*CD + ks*32 + quad*8;
            Bh[nt][ks] = ld8(qTh + off);
            Bl[nt][ks] = ld8(qTl + off);
        }
    f32x4 acc2[2][2] = {{z4(),z4()},{z4(),z4()}};
    float racc[4] = {0.f,0.f,0.f,0.f};

    for (int js=0;js<HD;js+=128){
        // phase A: S'[j][i] (m = j, n = i)
        f32x4 acc1[2][4];
        #pragma unroll
        for (int mt=0;mt<2;mt++)
            #pragma unroll
            for (int nt=0;nt<4;nt++) acc1[mt][nt] = z4();
        #pragma unroll
        for (int ks=0;ks<2;ks++){
            s16x8 Ah[2], Al[2];
            #pragma unroll
            for (int mt=0;mt<2;mt++){
                size_t off = ((size_t)bg*HD + js + wave*32 + mt*16 + ln)*CD + ks*32 + quad*8;
                Ah[mt] = ld8(zTh + off);
                Al[mt] = ld8(zTl + off);
            }
            #pragma unroll
            for (int mt=0;mt<2;mt++)
                #pragma unroll
                for (int nt=0;nt<4;nt++)
                    acc1[mt][nt] = mm3(Ah[mt], Al[mt], Bh[nt][ks], Bl[nt][ks], acc1[mt][nt]);
        }
        float bj8[8];
        #pragma unroll
        for (int mt=0;mt<2;mt++)
            #pragma unroll
            for (int rx=0;rx<4;rx++)
                bj8[mt*4+rx] = bias[(size_t)bg*HD + js + wave*32 + mt*16 + quad*4 + rx];
        __syncthreads();
        #pragma unroll
        for (int mt=0;mt<2;mt++)
            #pragma unroll
            for (int nt=0;nt<4;nt++){
                u16 hh[4], ll[4];
                #pragma unroll
                for (int rx=0;rx<4;rx++){
                    float e = __expf(fmaf(a, acc1[mt][nt][rx], bj8[mt*4+rx]));
                    racc[nt] += e;
                    split2(e, hh[rx], ll[rx]);
                }
                int row = nt*16 + ln;                        // i-local
                int c4  = wave*32 + mt*16 + quad*4;          // j-local
                int off = (row<<7) + ((((c4>>3) ^ (row&15))<<3) | (c4&7));
                *(ushort4*)&elh[off] = make_ushort4(hh[0],hh[1],hh[2],hh[3]);
                *(ushort4*)&ell[off] = make_ushort4(ll[0],ll[1],ll[2],ll[3]);
            }
        __syncthreads();
        // phase B: acc2[c][i] += mu * e^T  (m = c, n = i, k = j)
        #pragma unroll
        for (int ks2=0;ks2<4;ks2++){
            s16x8 A2h[2], A2l[2], B2h[2], B2l[2];
            #pragma unroll
            for (int mtN=0;mtN<2;mtN++){
                size_t off = ((size_t)bg*CD + cm + mtN*16 + ln)*HD + js + ks2*32 + quad*8;
                A2h[mtN] = ld8(muh + off);
                A2l[mtN] = ld8(mul_ + off);
            }
            #pragma unroll
            for (int nt2=0;nt2<2;nt2++){
                int il = in_ + nt2*16 + ln;
                int ob = (il<<7) + (((ks2*4+quad) ^ (il&15))<<3);
                B2h[nt2] = ld8(&elh[ob]);
                B2l[nt2] = ld8(&ell[ob]);
            }
            #pragma unroll
            for (int mtN=0;mtN<2;mtN++)
                #pragma unroll
                for (int nt2=0;nt2<2;nt2++)
                    acc2[mtN][nt2] = mm3(A2h[mtN], A2l[mtN], B2h[nt2], B2l[nt2], acc2[mtN][nt2]);
        }
    }
    #pragma unroll
    for (int nt=0;nt<4;nt++){
        float v = racc[nt];
        v += __shfl_xor(v,16); v += __shfl_xor(v,32);
        if (quad == 0) rl2[wave][nt*16 + ln] = v;
    }
    __syncthreads();
    #pragma unroll
    for (int nt2=0;nt2<2;nt2++){
        int il = in_ + nt2*16 + ln;
        float rinv = __builtin_amdgcn_rcpf(rl2[0][il]+rl2[1][il]+rl2[2][il]+rl2[3][il]);
        #pragma unroll
        for (int mtN=0;mtN<2;mtN++)
            #pragma unroll
            for (int rx=0;rx<4;rx++)
                out[((size_t)bg*CD + cm + mtN*16 + quad*4 + rx)*HD + i0 + il]
                    = acc2[mtN][nt2][rx] * rinv;
    }
}

extern "C" void kernel_launch(void* const* d_in, const int* in_sizes, int n_in,
                              void* d_out, int out_size, void* d_ws, size_t ws_size,
                              hipStream_t stream)
{
    (void)in_sizes; (void)n_in; (void)out_size; (void)ws_size;
    const float* q     = (const float*)d_in[0];
    const float* zeta  = (const float*)d_in[1];
    const float* alpha = (const float*)d_in[2];
    const float* mu    = (const float*)d_in[3];
    const float* beta  = (const float*)d_in[4];
    float* out = (float*)d_out;

    const size_t SZ = (size_t)NB*HD*CD;   // elements per tensor
    u16* qTh = (u16*)d_ws;
    u16* qTl = qTh + 1*SZ;
    u16* zTh = qTh + 2*SZ;
    u16* zTl = qTh + 3*SZ;
    u16* qNh = qTh + 4*SZ;
    u16* qNl = qTh + 5*SZ;
    u16* muh = qTh + 6*SZ;
    u16* mul_= qTh + 7*SZ;
    float* bias = (float*)(qTh + 8*SZ);
    float* r    = bias + (size_t)NB*HD;

    dim3 blk(256,1,1);
    int n4 = (int)(SZ/4);
    k_convert  <<<dim3(n4/256), blk, 0, stream>>>(q,  qNh, qNl, n4);
    k_convert  <<<dim3(n4/256), blk, 0, stream>>>(mu, muh, mul_, n4);
    k_transpose<<<dim3(HD/128, NB), blk, 0, stream>>>(q,    qTh, qTl);
    k_transpose<<<dim3(HD/128, NB), blk, 0, stream>>>(zeta, zTh, zTl);
    k_bias     <<<dim3(HD/256, NB), blk, 0, stream>>>(mu, beta, bias);

    k_rowsum<<<dim3(HD/64, NB), blk, 0, stream>>>(qTh,qTl,zTh,zTl,bias,alpha,r);
    k_update<<<dim3(HD/64, NB), blk, 0, stream>>>(qTh,qTl,zTh,zTl,qNh,qNl,bias,alpha,r);
    k_rowsum<<<dim3(HD/64, NB), blk, 0, stream>>>(qTh,qTl,zTh,zTl,bias,alpha,r);
    k_update<<<dim3(HD/64, NB), blk, 0, stream>>>(qTh,qTl,zTh,zTl,qNh,qNl,bias,alpha,r);
    k_final <<<dim3(HD/64, NB), blk, 0, stream>>>(qTh,qTl,zTh,zTl,muh,mul_,bias,alpha,out);
}